// Round 9
// baseline (117.585 us; speedup 1.0000x reference)
//
#include <hip/hip_runtime.h>
#include <hip/hip_bf16.h>

#define EPS 1e-8f

typedef __attribute__((ext_vector_type(8))) short short8;
typedef __attribute__((ext_vector_type(4))) float f32x4;

__device__ __forceinline__ unsigned short f2bf(float f) {
  union { float f; unsigned u; } v; v.f = f;
  unsigned r = v.u + 0x7fffu + ((v.u >> 16) & 1u);
  return (unsigned short)(r >> 16);
}
__device__ __forceinline__ float bf2f(unsigned short b) {
  union { unsigned u; float f; } v; v.u = ((unsigned)b) << 16;
  return v.f;
}
__device__ __forceinline__ unsigned pack_bf2(float lo, float hi) {
  unsigned r;
  asm("v_cvt_pk_bf16_f32 %0, %1, %2" : "=v"(r) : "v"(lo), "v"(hi));
  return r;
}
__device__ __forceinline__ float ulo(unsigned u) {
  union { unsigned u; float f; } v; v.u = u << 16; return v.f;
}
__device__ __forceinline__ float uhi(unsigned u) {
  union { unsigned u; float f; } v; v.u = u & 0xffff0000u; return v.f;
}

// ---------------- k0: build bf16 transposed weights --------------------------
__global__ __launch_bounds__(256) void k0_prep(const float* __restrict__ We1,
                                               const float* __restrict__ We2,
                                               const float* __restrict__ Wg1,
                                               const float* __restrict__ Wg2,
                                               const float* __restrict__ Wf,
                                               unsigned short* __restrict__ We1T,
                                               unsigned short* __restrict__ We2T,
                                               unsigned short* __restrict__ Wg1T,
                                               unsigned short* __restrict__ Wg2T,
                                               unsigned short* __restrict__ WfT) {
  int idx = blockIdx.x * 256 + threadIdx.x;     // 655360 total
  if (idx < 262144) {
    int n = idx >> 10, k = idx & 1023;
    We1T[idx] = f2bf(We1[k * 256 + n]);
  } else if (idx < 294912) {
    int e = idx - 262144;
    int n = e >> 8, k = e & 255;
    We2T[e] = f2bf(We2[k * 128 + n]);
  } else if (idx < 458752) {
    int e = idx - 294912;
    int n = e / 160, c = e % 160;
    float v = 0.f;
    if (c < 129) v = (n < 512) ? Wg1[c * 512 + n] : Wg1[(129 + c) * 512 + (n - 512)];
    Wg1T[e] = f2bf(v);
  } else if (idx < 589824) {
    int e = idx - 458752;
    int n = e >> 9, k = e & 511;
    Wg2T[e] = f2bf(Wg2[k * 256 + n]);
  } else {
    int e = idx - 589824;
    int n = e >> 8, k = e & 255;
    WfT[e] = f2bf(Wf[k * 256 + n]);
  }
}

// ---------------- k1: h_bf = bf16(relu(x @ We1 + be1)) -----------------------
__global__ __launch_bounds__(512, 2) void k1(const float* __restrict__ x,
                                             const unsigned short* __restrict__ We1T,
                                             const float* __restrict__ be1,
                                             unsigned short* __restrict__ h_bf) {
  __shared__ unsigned char As[2][8192];   // [16][256] bf16, swizzled
  int tid = threadIdx.x, lane = tid & 63, w = tid >> 6;
  int m0 = blockIdx.x * 16;
  int srow = tid >> 5, skk = (tid & 31) * 8;
  int cb = w * 32;
  int row = lane & 15, kg = (lane >> 4) * 8;

  f32x4 acc[2] = {{0,0,0,0},{0,0,0,0}};

  auto stage = [&](int kc, int buf) {
    const float* src = x + (size_t)(m0 + srow) * 1024 + kc * 256 + skk;
    float4 a = *reinterpret_cast<const float4*>(src);
    float4 b = *reinterpret_cast<const float4*>(src + 4);
    uint4 pv;
    pv.x = pack_bf2(a.x, a.y); pv.y = pack_bf2(a.z, a.w);
    pv.z = pack_bf2(b.x, b.y); pv.w = pack_bf2(b.z, b.w);
    int addr = (srow * 512 + skk * 2) ^ ((srow & 7) << 4);
    *reinterpret_cast<uint4*>(&As[buf][addr]) = pv;
  };

  stage(0, 0);
  __syncthreads();
  for (int kc = 0; kc < 4; ++kc) {
    if (kc < 3) stage(kc + 1, (kc + 1) & 1);
    short8 breg[2][8];
#pragma unroll
    for (int cf = 0; cf < 2; ++cf)
#pragma unroll
      for (int ks = 0; ks < 8; ++ks)
        breg[cf][ks] = *reinterpret_cast<const short8*>(
            We1T + (size_t)(cb + cf * 16 + row) * 1024 + kc * 256 + ks * 32 + kg);
    const unsigned char* hc = &As[kc & 1][0];
#pragma unroll
    for (int ks = 0; ks < 8; ++ks) {
      int aoff = (row * 512 + ks * 64 + kg * 2) ^ ((row & 7) << 4);
      short8 af = *reinterpret_cast<const short8*>(hc + aoff);
      acc[0] = __builtin_amdgcn_mfma_f32_16x16x32_bf16(af, breg[0][ks], acc[0], 0, 0, 0);
      acc[1] = __builtin_amdgcn_mfma_f32_16x16x32_bf16(af, breg[1][ks], acc[1], 0, 0, 0);
    }
    __syncthreads();
  }
#pragma unroll
  for (int cf = 0; cf < 2; ++cf) {
    int col = cb + cf * 16 + row;
    float bias = be1[col];
#pragma unroll
    for (int r = 0; r < 4; ++r) {
      int orow = m0 + (lane >> 4) * 4 + r;
      h_bf[(size_t)orow * 256 + col] = f2bf(fmaxf(acc[cf][r] + bias, 0.f));
    }
  }
}

// ---------------- k2a: z = h@We2+be2 -> LN(T, ddof=1) -> zc [4096][160] bf16 --
__global__ __launch_bounds__(256) void k2a(const unsigned short* __restrict__ h_bf,
                                           const unsigned short* __restrict__ We2T,
                                           const float* __restrict__ be2,
                                           const float* __restrict__ gamma,
                                           const float* __restrict__ beta,
                                           unsigned short* __restrict__ zc) {
  __shared__ unsigned char zcs[16384];   // [32][256] bf16 swizzled (h tile)
  __shared__ float zb[32][132];
  int b = blockIdx.x, tid = threadIdx.x, lane = tid & 63, w = tid >> 6;
  int row = lane & 15, kg = (lane >> 4) * 8;

  {
    int srow = tid >> 3, skk = (tid & 7) * 32;
#pragma unroll
    for (int q = 0; q < 4; ++q) {
      short8 v = *reinterpret_cast<const short8*>(
          h_bf + (size_t)(b * 32 + srow) * 256 + skk + q * 8);
      int addr = (srow * 512 + (skk + q * 8) * 2) ^ ((srow & 7) << 4);
      *reinterpret_cast<short8*>(&zcs[addr]) = v;
    }
  }
  short8 breg1[2][8];
#pragma unroll
  for (int cf = 0; cf < 2; ++cf)
#pragma unroll
    for (int ks = 0; ks < 8; ++ks)
      breg1[cf][ks] = *reinterpret_cast<const short8*>(
          We2T + (size_t)(w * 32 + cf * 16 + row) * 256 + ks * 32 + kg);
  __syncthreads();

  {
    f32x4 acc[2][2] = {{{0,0,0,0},{0,0,0,0}},{{0,0,0,0},{0,0,0,0}}};
#pragma unroll
    for (int ks = 0; ks < 8; ++ks) {
      int a0off = (row * 512 + ks * 64 + kg * 2) ^ ((row & 7) << 4);
      int a1off = ((16 + row) * 512 + ks * 64 + kg * 2) ^ ((row & 7) << 4);
      short8 a0 = *reinterpret_cast<const short8*>(&zcs[a0off]);
      short8 a1 = *reinterpret_cast<const short8*>(&zcs[a1off]);
#pragma unroll
      for (int cf = 0; cf < 2; ++cf) {
        acc[0][cf] = __builtin_amdgcn_mfma_f32_16x16x32_bf16(a0, breg1[cf][ks], acc[0][cf], 0, 0, 0);
        acc[1][cf] = __builtin_amdgcn_mfma_f32_16x16x32_bf16(a1, breg1[cf][ks], acc[1][cf], 0, 0, 0);
      }
    }
#pragma unroll
    for (int rf = 0; rf < 2; ++rf)
#pragma unroll
      for (int cf = 0; cf < 2; ++cf) {
        int col = w * 32 + cf * 16 + row;
        float bias = be2[col];
#pragma unroll
        for (int r = 0; r < 4; ++r)
          zb[rf * 16 + (lane >> 4) * 4 + r][col] = acc[rf][cf][r] + bias;
      }
  }
  __syncthreads();

  if (tid < 128) {
    float s = 0.f, s2 = 0.f;
#pragma unroll 4
    for (int t = 0; t < 32; ++t) { float v = zb[t][tid]; s += v; s2 += v * v; }
    float mu = s * (1.f / 32.f);
    float var = (s2 - 32.f * mu * mu) * (1.f / 31.f);
    float rs = 1.f / sqrtf(fmaxf(var, 0.f) + EPS);
    float g = gamma[tid], be = beta[tid];
#pragma unroll 4
    for (int t = 0; t < 32; ++t)
      zc[(size_t)(b * 32 + t) * 160 + tid] = f2bf((zb[t][tid] - mu) * rs * g + be);
  } else if (tid < 160) {
    for (int t = 0; t < 32; ++t)
      zc[(size_t)(b * 32 + t) * 160 + tid] = (tid == 128) ? f2bf((float)t) : 0;
  }
}

// ---------------- k2b: g_all = zc @ Wg1T (+bg1 for n<512), M=4096 N=1024 K=160
__global__ __launch_bounds__(512, 4) void k2b(const unsigned short* __restrict__ zc,
                                              const unsigned short* __restrict__ Wg1T,
                                              const float* __restrict__ bg1,
                                              unsigned short* __restrict__ g_all) {
  __shared__ unsigned char As[16384];   // [32][256] bf16 swizzled
  int m0 = (blockIdx.x >> 2) * 32;
  int n0 = (blockIdx.x & 3) * 256;
  int tid = threadIdx.x, lane = tid & 63, w = tid >> 6;
  int row = lane & 15, kg = (lane >> 4) * 8;
  int c0 = n0 + w * 32;

  for (int ch = tid; ch < 640; ch += 512) {
    int r = ch / 20, c16 = ch % 20;
    short8 v = *reinterpret_cast<const short8*>(zc + (size_t)(m0 + r) * 160 + c16 * 8);
    int addr = (r * 512 + c16 * 16) ^ ((r & 7) << 4);
    *reinterpret_cast<short8*>(&As[addr]) = v;
  }
  short8 breg[2][5];
#pragma unroll
  for (int cf = 0; cf < 2; ++cf)
#pragma unroll
    for (int ks = 0; ks < 5; ++ks)
      breg[cf][ks] = *reinterpret_cast<const short8*>(
          Wg1T + (size_t)(c0 + cf * 16 + row) * 160 + ks * 32 + kg);
  __syncthreads();

  f32x4 acc[2][2] = {{{0,0,0,0},{0,0,0,0}},{{0,0,0,0},{0,0,0,0}}};
#pragma unroll
  for (int ks = 0; ks < 5; ++ks) {
    int a0off = (row * 512 + ks * 64 + kg * 2) ^ ((row & 7) << 4);
    int a1off = ((16 + row) * 512 + ks * 64 + kg * 2) ^ ((row & 7) << 4);
    short8 a0 = *reinterpret_cast<const short8*>(&As[a0off]);
    short8 a1 = *reinterpret_cast<const short8*>(&As[a1off]);
#pragma unroll
    for (int cf = 0; cf < 2; ++cf) {
      acc[0][cf] = __builtin_amdgcn_mfma_f32_16x16x32_bf16(a0, breg[cf][ks], acc[0][cf], 0, 0, 0);
      acc[1][cf] = __builtin_amdgcn_mfma_f32_16x16x32_bf16(a1, breg[cf][ks], acc[1][cf], 0, 0, 0);
    }
  }
#pragma unroll
  for (int cf = 0; cf < 2; ++cf) {
    int n = c0 + cf * 16 + row;
    float bias = (n < 512) ? bg1[n] : 0.f;
#pragma unroll
    for (int rf = 0; rf < 2; ++rf)
#pragma unroll
      for (int r = 0; r < 4; ++r) {
        int mrow = m0 + rf * 16 + (lane >> 4) * 4 + r;
        g_all[((size_t)mrow << 10) + n] = f2bf(acc[rf][cf][r] + bias);
      }
  }
}

// ---------------- k3: barrier-free pair GEMM ---------------------------------
// gi (f32, 32KB, broadcast reads) + gj (bf16, 32KB, swizzled) staged ONCE.
// Main loop has NO barriers, NO H tile: A-frags built in registers per K-step.
__global__ __launch_bounds__(512, 2) void k3(const unsigned short* __restrict__ g_all,
                                             const unsigned short* __restrict__ Wg2T,
                                             const float* __restrict__ bg2,
                                             float* __restrict__ all_gp) {
  __shared__ float giL[8192];            // [16][512] f32, linear
  __shared__ unsigned char gjL[32768];   // [32][512] bf16, swizzled
  int b = blockIdx.x >> 1, hi = blockIdx.x & 1;
  int ii0 = hi * 16;
  int tid = threadIdx.x, lane = tid & 63, w = tid >> 6;
  int r = lane & 15, q = lane >> 4;
  int cb = w * 32;

  // B-regs: Wg2T cols cb..cb+31, full K=512  (128 regs)
  short8 breg[2][16];
#pragma unroll
  for (int cf = 0; cf < 2; ++cf)
#pragma unroll
    for (int ks = 0; ks < 16; ++ks)
      breg[cf][ks] = *reinterpret_cast<const short8*>(
          Wg2T + (size_t)(cb + cf * 16 + r) * 512 + ks * 32 + q * 8);

  // stage gi rows ii0..ii0+15 as f32 (linear)
  for (int e = tid; e < 1024; e += 512) {
    int rr = e >> 6, c8 = (e & 63) << 3;
    short8 v = *reinterpret_cast<const short8*>(
        g_all + ((size_t)(b * 32 + ii0 + rr) << 10) + c8);
    float4 fa, fb;
    fa.x = bf2f((unsigned short)v[0]); fa.y = bf2f((unsigned short)v[1]);
    fa.z = bf2f((unsigned short)v[2]); fa.w = bf2f((unsigned short)v[3]);
    fb.x = bf2f((unsigned short)v[4]); fb.y = bf2f((unsigned short)v[5]);
    fb.z = bf2f((unsigned short)v[6]); fb.w = bf2f((unsigned short)v[7]);
    *reinterpret_cast<float4*>(&giL[rr * 512 + c8]) = fa;
    *reinterpret_cast<float4*>(&giL[rr * 512 + c8 + 4]) = fb;
  }
  // stage gj rows 0..31 as bf16 (swizzled)
  for (int e = tid; e < 2048; e += 512) {
    int rr = e >> 6, c8 = (e & 63) << 3;
    short8 v = *reinterpret_cast<const short8*>(
        g_all + ((size_t)(b * 32 + rr) << 10) + 512 + c8);
    int addr = (rr * 1024 + c8 * 2) ^ ((rr & 7) << 4);
    *reinterpret_cast<short8*>(&gjL[addr]) = v;
  }
  float biasv[2] = { bg2[cb + r], bg2[cb + 16 + r] };
  float accsum[2] = { 0.f, 0.f };
  __syncthreads();

  // per-lane swizzled gj bases (even/odd ks; +16384 bytes for row r+16)
  int swz = (r & 7) << 4;
  int gjE = (r * 1024 + q * 16) ^ swz;
  int gjO = (r * 1024 + 64 + q * 16) ^ swz;

  auto mkfrag = [&](short8 gj, float4 a, float4 bb) {
    uint4 u = *reinterpret_cast<uint4*>(&gj);
    float f0 = fmaxf(a.x + ulo(u.x), 0.f);
    float f1 = fmaxf(a.y + uhi(u.x), 0.f);
    float f2 = fmaxf(a.z + ulo(u.y), 0.f);
    float f3 = fmaxf(a.w + uhi(u.y), 0.f);
    float f4 = fmaxf(bb.x + ulo(u.z), 0.f);
    float f5 = fmaxf(bb.y + uhi(u.z), 0.f);
    float f6 = fmaxf(bb.z + ulo(u.w), 0.f);
    float f7 = fmaxf(bb.w + uhi(u.w), 0.f);
    uint4 p;
    p.x = pack_bf2(f0, f1); p.y = pack_bf2(f2, f3);
    p.z = pack_bf2(f4, f5); p.w = pack_bf2(f6, f7);
    return *reinterpret_cast<short8*>(&p);
  };

#pragma unroll 1
  for (int il = 0; il < 16; ++il) {
    const float* gib = &giL[il * 512 + q * 8];
    f32x4 acc00 = {0,0,0,0}, acc01 = {0,0,0,0}, acc10 = {0,0,0,0}, acc11 = {0,0,0,0};
    short8 rgj0[2], rgj1[2];
    float4 rgiA[2], rgiB[2];
    rgj0[0] = *reinterpret_cast<const short8*>(gjL + gjE);
    rgj1[0] = *reinterpret_cast<const short8*>(gjL + gjE + 16384);
    rgiA[0] = *reinterpret_cast<const float4*>(gib);
    rgiB[0] = *reinterpret_cast<const float4*>(gib + 4);
#pragma unroll
    for (int ks = 0; ks < 16; ++ks) {
      int cs = ks & 1, ns = cs ^ 1;
      if (ks < 15) {
        int koff = ((ks + 1) >> 1) * 128;
        int base = ((ks + 1) & 1) ? gjO : gjE;
        rgj0[ns] = *reinterpret_cast<const short8*>(gjL + base + koff);
        rgj1[ns] = *reinterpret_cast<const short8*>(gjL + base + koff + 16384);
        rgiA[ns] = *reinterpret_cast<const float4*>(gib + (ks + 1) * 32);
        rgiB[ns] = *reinterpret_cast<const float4*>(gib + (ks + 1) * 32 + 4);
      }
      short8 af0 = mkfrag(rgj0[cs], rgiA[cs], rgiB[cs]);
      short8 af1 = mkfrag(rgj1[cs], rgiA[cs], rgiB[cs]);
      acc00 = __builtin_amdgcn_mfma_f32_16x16x32_bf16(af0, breg[0][ks], acc00, 0, 0, 0);
      acc01 = __builtin_amdgcn_mfma_f32_16x16x32_bf16(af0, breg[1][ks], acc01, 0, 0, 0);
      acc10 = __builtin_amdgcn_mfma_f32_16x16x32_bf16(af1, breg[0][ks], acc10, 0, 0, 0);
      acc11 = __builtin_amdgcn_mfma_f32_16x16x32_bf16(af1, breg[1][ks], acc11, 0, 0, 0);
    }
#pragma unroll
    for (int e = 0; e < 4; ++e) {
      accsum[0] += fmaxf(acc00[e] + biasv[0], 0.f) + fmaxf(acc10[e] + biasv[0], 0.f);
      accsum[1] += fmaxf(acc01[e] + biasv[1], 0.f) + fmaxf(acc11[e] + biasv[1], 0.f);
    }
  }

#pragma unroll
  for (int cf = 0; cf < 2; ++cf) {
    accsum[cf] += __shfl_xor(accsum[cf], 16, 64);
    accsum[cf] += __shfl_xor(accsum[cf], 32, 64);
  }
  if ((lane >> 4) == 0) {
#pragma unroll
    for (int cf = 0; cf < 2; ++cf)
      all_gp[(size_t)(hi * 128 + b) * 256 + cb + cf * 16 + lane] = accsum[cf];
  }
}

// ---------------- k4: head (MFMA), sums 2 all_gp partials --------------------
__global__ __launch_bounds__(512) void k4(const float* __restrict__ all_gp,
                                          const unsigned short* __restrict__ WfT,
                                          const float* __restrict__ bfv,
                                          const float* __restrict__ Wy,
                                          const float* __restrict__ by,
                                          float* __restrict__ out) {
  __shared__ unsigned char As[8192];      // [16][256] bf16 swizzled
  __shared__ float fh[16][264];
  __shared__ float wys[1024];
  __shared__ float yvs[16][4];
  int tid = threadIdx.x, lane = tid & 63, w = tid >> 6;
  int row = lane & 15, kg = (lane >> 4) * 8;
  int m0 = blockIdx.x * 16;

  {
    int r = tid >> 5, c8 = (tid & 31) * 8;
    float s[8];
#pragma unroll
    for (int e = 0; e < 8; ++e) s[e] = 0.f;
#pragma unroll
    for (int q = 0; q < 2; ++q) {
      const float* p0 = all_gp + (size_t)(q * 128 + m0 + r) * 256 + c8;
      float4 a0 = *reinterpret_cast<const float4*>(p0);
      float4 a1 = *reinterpret_cast<const float4*>(p0 + 4);
      s[0] += a0.x; s[1] += a0.y; s[2] += a0.z; s[3] += a0.w;
      s[4] += a1.x; s[5] += a1.y; s[6] += a1.z; s[7] += a1.w;
    }
    uint4 pv;
    pv.x = pack_bf2(s[0], s[1]); pv.y = pack_bf2(s[2], s[3]);
    pv.z = pack_bf2(s[4], s[5]); pv.w = pack_bf2(s[6], s[7]);
    int addr = (r * 512 + c8 * 2) ^ ((r & 7) << 4);
    *reinterpret_cast<uint4*>(&As[addr]) = pv;
  }
  wys[tid] = Wy[tid];
  wys[tid + 512] = Wy[tid + 512];
  short8 breg[2][8];
#pragma unroll
  for (int cf = 0; cf < 2; ++cf)
#pragma unroll
    for (int ks = 0; ks < 8; ++ks)
      breg[cf][ks] = *reinterpret_cast<const short8*>(
          WfT + (size_t)(w * 32 + cf * 16 + row) * 256 + ks * 32 + kg);
  __syncthreads();

  f32x4 acc[2] = {{0,0,0,0},{0,0,0,0}};
#pragma unroll
  for (int ks = 0; ks < 8; ++ks) {
    int aoff = (row * 512 + ks * 64 + kg * 2) ^ ((row & 7) << 4);
    short8 af = *reinterpret_cast<const short8*>(&As[aoff]);
    acc[0] = __builtin_amdgcn_mfma_f32_16x16x32_bf16(af, breg[0][ks], acc[0], 0, 0, 0);
    acc[1] = __builtin_amdgcn_mfma_f32_16x16x32_bf16(af, breg[1][ks], acc[1], 0, 0, 0);
  }
#pragma unroll
  for (int cf = 0; cf < 2; ++cf) {
    int col = w * 32 + cf * 16 + row;
    float bias = bfv[col];
#pragma unroll
    for (int r = 0; r < 4; ++r)
      fh[(lane >> 4) * 4 + r][col] = fmaxf(acc[cf][r] + bias, 0.f);
  }
  __syncthreads();

  if (tid < 64) {
    int r = tid >> 2, o = tid & 3;
    float y = by[o];
#pragma unroll 4
    for (int k = 0; k < 256; ++k) y += fh[r][k] * wys[k * 4 + o];
    yvs[r][o] = y;
    out[(m0 + r) * 4 + o] = y;
  }
  __syncthreads();
  if (tid < 16) {
    int am = 0;
    float best = yvs[tid][0];
#pragma unroll
    for (int o = 1; o < 4; ++o)
      if (yvs[tid][o] > best) { best = yvs[tid][o]; am = o; }
    out[512 + m0 + tid] = (float)am;
  }
}

extern "C" void kernel_launch(void* const* d_in, const int* in_sizes, int n_in,
                              void* d_out, int out_size, void* d_ws, size_t ws_size,
                              hipStream_t stream) {
  const float* x     = (const float*)d_in[0];
  const float* We1   = (const float*)d_in[1];
  const float* be1   = (const float*)d_in[2];
  const float* We2   = (const float*)d_in[3];
  const float* be2   = (const float*)d_in[4];
  const float* gamma = (const float*)d_in[5];
  const float* beta  = (const float*)d_in[6];
  const float* Wg1   = (const float*)d_in[7];
  const float* bg1   = (const float*)d_in[8];
  const float* Wg2   = (const float*)d_in[9];
  const float* bg2   = (const float*)d_in[10];
  const float* Wf    = (const float*)d_in[11];
  const float* bff   = (const float*)d_in[12];
  const float* Wy    = (const float*)d_in[13];
  const float* by    = (const float*)d_in[14];

  char* ws = (char*)d_ws;
  unsigned short* h_bf  = (unsigned short*)(ws + 0);          // 2 MB
  unsigned short* g_all = (unsigned short*)(ws + 2097152);    // 8 MB
  unsigned short* We1T  = (unsigned short*)(ws + 10485760);   // 512 KB
  unsigned short* We2T  = (unsigned short*)(ws + 11010048);   // 64 KB
  unsigned short* Wg1T  = (unsigned short*)(ws + 11075584);   // 320 KB
  unsigned short* Wg2T  = (unsigned short*)(ws + 11403264);   // 256 KB
  float*          all_gp= (float*)(ws + 11665408);            // 256 KB [2][128][256]
  unsigned short* WfT   = (unsigned short*)(ws + 11927552);   // 128 KB
  unsigned short* zc    = (unsigned short*)(ws + 12058624);   // 1.31 MB
  float*          out   = (float*)d_out;

  k0_prep<<<2560, 256, 0, stream>>>(We1, We2, Wg1, Wg2, Wf, We1T, We2T, Wg1T, Wg2T, WfT);
  k1<<<256, 512, 0, stream>>>(x, We1T, be1, h_bf);
  k2a<<<128, 256, 0, stream>>>(h_bf, We2T, be2, gamma, beta, zc);
  k2b<<<512, 512, 0, stream>>>(zc, Wg1T, bg1, g_all);
  k3<<<256, 512, 0, stream>>>(g_all, Wg2T, bg2, all_gp);
  k4<<<8, 512, 0, stream>>>(all_gp, WfT, bff, Wy, by, out);
}

// Round 10
// 85.956 us; speedup vs baseline: 1.3680x; 1.3680x over previous
//
#include <hip/hip_runtime.h>
#include <hip/hip_bf16.h>

#define EPS 1e-8f

typedef __attribute__((ext_vector_type(8))) short short8;
typedef __attribute__((ext_vector_type(4))) float f32x4;

__device__ __forceinline__ unsigned short f2bf(float f) {
  union { float f; unsigned u; } v; v.f = f;
  unsigned r = v.u + 0x7fffu + ((v.u >> 16) & 1u);
  return (unsigned short)(r >> 16);
}
__device__ __forceinline__ float bf2f(unsigned short b) {
  union { unsigned u; float f; } v; v.u = ((unsigned)b) << 16;
  return v.f;
}
__device__ __forceinline__ unsigned pack_bf2(float lo, float hi) {
  unsigned r;
  asm("v_cvt_pk_bf16_f32 %0, %1, %2" : "=v"(r) : "v"(lo), "v"(hi));
  return r;
}

// ---------------- k0: coalesced LDS-tiled transposes f32 -> bf16 -------------
// 640 blocks of one 32x32 tile each: We1(256) We2(32) Wg2(128) Wf(64) Wg1(160)
__global__ __launch_bounds__(256) void k0_prep(const float* __restrict__ We1,
                                               const float* __restrict__ We2,
                                               const float* __restrict__ Wg1,
                                               const float* __restrict__ Wg2,
                                               const float* __restrict__ Wf,
                                               unsigned short* __restrict__ We1T,
                                               unsigned short* __restrict__ We2T,
                                               unsigned short* __restrict__ Wg1T,
                                               unsigned short* __restrict__ Wg2T,
                                               unsigned short* __restrict__ WfT) {
  __shared__ float ld[32][33];
  int t = blockIdx.x, tid = threadIdx.x;
  int r0 = tid >> 5, c = tid & 31;

  if (t < 256) {            // We1: 1024x256 -> 256x1024
    int rb = (t >> 3) * 32, cb = (t & 7) * 32;
#pragma unroll
    for (int j = 0; j < 4; ++j)
      ld[r0 + j * 8][c] = We1[(size_t)(rb + r0 + j * 8) * 256 + cb + c];
    __syncthreads();
#pragma unroll
    for (int j = 0; j < 4; ++j)
      We1T[(size_t)(cb + r0 + j * 8) * 1024 + rb + c] = f2bf(ld[c][r0 + j * 8]);
  } else if (t < 288) {     // We2: 256x128 -> 128x256
    int u = t - 256;
    int rb = (u >> 2) * 32, cb = (u & 3) * 32;
#pragma unroll
    for (int j = 0; j < 4; ++j)
      ld[r0 + j * 8][c] = We2[(size_t)(rb + r0 + j * 8) * 128 + cb + c];
    __syncthreads();
#pragma unroll
    for (int j = 0; j < 4; ++j)
      We2T[(size_t)(cb + r0 + j * 8) * 256 + rb + c] = f2bf(ld[c][r0 + j * 8]);
  } else if (t < 416) {     // Wg2: 512x256 -> 256x512
    int u = t - 288;
    int rb = (u >> 3) * 32, cb = (u & 7) * 32;
#pragma unroll
    for (int j = 0; j < 4; ++j)
      ld[r0 + j * 8][c] = Wg2[(size_t)(rb + r0 + j * 8) * 256 + cb + c];
    __syncthreads();
#pragma unroll
    for (int j = 0; j < 4; ++j)
      Wg2T[(size_t)(cb + r0 + j * 8) * 512 + rb + c] = f2bf(ld[c][r0 + j * 8]);
  } else if (t < 480) {     // Wf: 256x256 -> 256x256
    int u = t - 416;
    int rb = (u >> 3) * 32, cb = (u & 7) * 32;
#pragma unroll
    for (int j = 0; j < 4; ++j)
      ld[r0 + j * 8][c] = Wf[(size_t)(rb + r0 + j * 8) * 256 + cb + c];
    __syncthreads();
#pragma unroll
    for (int j = 0; j < 4; ++j)
      WfT[(size_t)(cb + r0 + j * 8) * 256 + rb + c] = f2bf(ld[c][r0 + j * 8]);
  } else {                  // Wg1: 258x512 -> Wg1T[1024][160] (K-pad 129->160)
    int u = t - 480;
    int nb = (u / 5) * 32, cb5 = (u % 5) * 32;
#pragma unroll
    for (int j = 0; j < 4; ++j) {
      int cloc = r0 + j * 8, cidx = cb5 + cloc, n = nb + c;
      float v = 0.f;
      if (cidx < 129)
        v = (n < 512) ? Wg1[(size_t)cidx * 512 + n]
                      : Wg1[(size_t)(129 + cidx) * 512 + (n - 512)];
      ld[cloc][c] = v;
    }
    __syncthreads();
#pragma unroll
    for (int j = 0; j < 4; ++j)
      Wg1T[(size_t)(nb + r0 + j * 8) * 160 + cb5 + c] = f2bf(ld[c][r0 + j * 8]);
  }
}

// ---------------- k1f: fused h=relu(x@We1+be1) -> z=h@We2+be2 -> LN -> zc ----
// grid 128 (one b each), 512 thr = 8 waves x 32 cols, M=32 rows.
__global__ __launch_bounds__(512) void k1f(const float* __restrict__ x,
                                           const unsigned short* __restrict__ We1T,
                                           const float* __restrict__ be1,
                                           const unsigned short* __restrict__ We2T,
                                           const float* __restrict__ be2,
                                           const float* __restrict__ gamma,
                                           const float* __restrict__ beta,
                                           unsigned short* __restrict__ zc) {
  __shared__ unsigned char As[2][16384];   // [32][256] bf16 swizzled, dbuf
  __shared__ float zb[32][132];
  int b = blockIdx.x, tid = threadIdx.x, lane = tid & 63, w = tid >> 6;
  int row = lane & 15, kg = (lane >> 4) * 8;
  int cb = w * 32;
  int srow = tid >> 4, sc16 = (tid & 15) * 16;

  auto stage = [&](int kc, int buf) {
    const float* src = x + (size_t)(b * 32 + srow) * 1024 + kc * 256 + sc16;
    float4 a  = reinterpret_cast<const float4*>(src)[0];
    float4 bb = reinterpret_cast<const float4*>(src)[1];
    float4 cc = reinterpret_cast<const float4*>(src)[2];
    float4 dd = reinterpret_cast<const float4*>(src)[3];
    uint4 p0, p1;
    p0.x = pack_bf2(a.x, a.y);  p0.y = pack_bf2(a.z, a.w);
    p0.z = pack_bf2(bb.x, bb.y); p0.w = pack_bf2(bb.z, bb.w);
    p1.x = pack_bf2(cc.x, cc.y); p1.y = pack_bf2(cc.z, cc.w);
    p1.z = pack_bf2(dd.x, dd.y); p1.w = pack_bf2(dd.z, dd.w);
    int base = srow * 512 + sc16 * 2, swz = (srow & 7) << 4;
    *reinterpret_cast<uint4*>(&As[buf][base ^ swz]) = p0;
    *reinterpret_cast<uint4*>(&As[buf][(base + 16) ^ swz]) = p1;
  };

  f32x4 acc1[2][2] = {{{0,0,0,0},{0,0,0,0}},{{0,0,0,0},{0,0,0,0}}};
  stage(0, 0);
  __syncthreads();
  for (int kc = 0; kc < 4; ++kc) {
    if (kc < 3) stage(kc + 1, (kc + 1) & 1);
    short8 breg[2][8];
#pragma unroll
    for (int cf = 0; cf < 2; ++cf)
#pragma unroll
      for (int ks = 0; ks < 8; ++ks)
        breg[cf][ks] = *reinterpret_cast<const short8*>(
            We1T + (size_t)(cb + cf * 16 + row) * 1024 + kc * 256 + ks * 32 + kg);
    const unsigned char* hc = &As[kc & 1][0];
#pragma unroll
    for (int ks = 0; ks < 8; ++ks) {
      int a0off = (row * 512 + ks * 64 + kg * 2) ^ ((row & 7) << 4);
      int a1off = ((16 + row) * 512 + ks * 64 + kg * 2) ^ ((row & 7) << 4);
      short8 a0 = *reinterpret_cast<const short8*>(hc + a0off);
      short8 a1 = *reinterpret_cast<const short8*>(hc + a1off);
#pragma unroll
      for (int cf = 0; cf < 2; ++cf) {
        acc1[0][cf] = __builtin_amdgcn_mfma_f32_16x16x32_bf16(a0, breg[cf][ks], acc1[0][cf], 0, 0, 0);
        acc1[1][cf] = __builtin_amdgcn_mfma_f32_16x16x32_bf16(a1, breg[cf][ks], acc1[1][cf], 0, 0, 0);
      }
    }
    __syncthreads();
  }

  // h = relu(acc1 + be1) -> As[0] (zcs layout, swizzled)
#pragma unroll
  for (int cf = 0; cf < 2; ++cf) {
    int col = cb + cf * 16 + row;
    float bias = be1[col];
#pragma unroll
    for (int rf = 0; rf < 2; ++rf)
#pragma unroll
      for (int r = 0; r < 4; ++r) {
        int rr = rf * 16 + (lane >> 4) * 4 + r;
        unsigned short hv = f2bf(fmaxf(acc1[rf][cf][r] + bias, 0.f));
        int addr = (rr * 512 + col * 2) ^ ((rr & 7) << 4);
        *reinterpret_cast<unsigned short*>(&As[0][addr]) = hv;
      }
  }
  __syncthreads();

  // GEMM2: z = h @ We2 + be2
  short8 breg1[2][8];
#pragma unroll
  for (int cf = 0; cf < 2; ++cf)
#pragma unroll
    for (int ks = 0; ks < 8; ++ks)
      breg1[cf][ks] = *reinterpret_cast<const short8*>(
          We2T + (size_t)(w * 32 + cf * 16 + row) * 256 + ks * 32 + kg);
  {
    f32x4 acc[2][2] = {{{0,0,0,0},{0,0,0,0}},{{0,0,0,0},{0,0,0,0}}};
    const unsigned char* hc = &As[0][0];
#pragma unroll
    for (int ks = 0; ks < 8; ++ks) {
      int a0off = (row * 512 + ks * 64 + kg * 2) ^ ((row & 7) << 4);
      int a1off = ((16 + row) * 512 + ks * 64 + kg * 2) ^ ((row & 7) << 4);
      short8 a0 = *reinterpret_cast<const short8*>(hc + a0off);
      short8 a1 = *reinterpret_cast<const short8*>(hc + a1off);
#pragma unroll
      for (int cf = 0; cf < 2; ++cf) {
        acc[0][cf] = __builtin_amdgcn_mfma_f32_16x16x32_bf16(a0, breg1[cf][ks], acc[0][cf], 0, 0, 0);
        acc[1][cf] = __builtin_amdgcn_mfma_f32_16x16x32_bf16(a1, breg1[cf][ks], acc[1][cf], 0, 0, 0);
      }
    }
#pragma unroll
    for (int rf = 0; rf < 2; ++rf)
#pragma unroll
      for (int cf = 0; cf < 2; ++cf) {
        int col = w * 32 + cf * 16 + row;
        if (col < 128) {
          float bias = be2[col];
#pragma unroll
          for (int r = 0; r < 4; ++r)
            zb[rf * 16 + (lane >> 4) * 4 + r][col] = acc[rf][cf][r] + bias;
        }
      }
  }
  __syncthreads();

  // LN over T (ddof=1), write zc global (+tag at 128, pad to 160)
  if (tid < 128) {
    float s = 0.f, s2 = 0.f;
#pragma unroll 4
    for (int t = 0; t < 32; ++t) { float v = zb[t][tid]; s += v; s2 += v * v; }
    float mu = s * (1.f / 32.f);
    float var = (s2 - 32.f * mu * mu) * (1.f / 31.f);
    float rs = 1.f / sqrtf(fmaxf(var, 0.f) + EPS);
    float g = gamma[tid], be = beta[tid];
#pragma unroll 4
    for (int t = 0; t < 32; ++t)
      zc[(size_t)(b * 32 + t) * 160 + tid] = f2bf((zb[t][tid] - mu) * rs * g + be);
  } else if (tid < 160) {
    for (int t = 0; t < 32; ++t)
      zc[(size_t)(b * 32 + t) * 160 + tid] = (tid == 128) ? f2bf((float)t) : 0;
  }
}

// NOTE: We2 is 256x128 so GEMM2 cols are 0..127; waves w>=4 compute cols>=128
// whose breg1 reads fall inside We2T padding region — guarded by col<128 on the
// zb write. We2T buffer is 128x256; reads at col>=128 would be OOB, so clamp:
// (handled by allocating We2T with 256 rows worth of space — see kernel_launch)

// ---------------- k2b: g_all = zc @ Wg1T (+bg1 for n<512), M=4096 N=1024 K=160
__global__ __launch_bounds__(512, 4) void k2b(const unsigned short* __restrict__ zc,
                                              const unsigned short* __restrict__ Wg1T,
                                              const float* __restrict__ bg1,
                                              unsigned short* __restrict__ g_all) {
  __shared__ unsigned char As[16384];   // [32][256] bf16 swizzled
  int m0 = (blockIdx.x >> 2) * 32;
  int n0 = (blockIdx.x & 3) * 256;
  int tid = threadIdx.x, lane = tid & 63, w = tid >> 6;
  int row = lane & 15, kg = (lane >> 4) * 8;
  int c0 = n0 + w * 32;

  for (int ch = tid; ch < 640; ch += 512) {
    int r = ch / 20, c16 = ch % 20;
    short8 v = *reinterpret_cast<const short8*>(zc + (size_t)(m0 + r) * 160 + c16 * 8);
    int addr = (r * 512 + c16 * 16) ^ ((r & 7) << 4);
    *reinterpret_cast<short8*>(&As[addr]) = v;
  }
  short8 breg[2][5];
#pragma unroll
  for (int cf = 0; cf < 2; ++cf)
#pragma unroll
    for (int ks = 0; ks < 5; ++ks)
      breg[cf][ks] = *reinterpret_cast<const short8*>(
          Wg1T + (size_t)(c0 + cf * 16 + row) * 160 + ks * 32 + kg);
  __syncthreads();

  f32x4 acc[2][2] = {{{0,0,0,0},{0,0,0,0}},{{0,0,0,0},{0,0,0,0}}};
#pragma unroll
  for (int ks = 0; ks < 5; ++ks) {
    int a0off = (row * 512 + ks * 64 + kg * 2) ^ ((row & 7) << 4);
    int a1off = ((16 + row) * 512 + ks * 64 + kg * 2) ^ ((row & 7) << 4);
    short8 a0 = *reinterpret_cast<const short8*>(&As[a0off]);
    short8 a1 = *reinterpret_cast<const short8*>(&As[a1off]);
#pragma unroll
    for (int cf = 0; cf < 2; ++cf) {
      acc[0][cf] = __builtin_amdgcn_mfma_f32_16x16x32_bf16(a0, breg[cf][ks], acc[0][cf], 0, 0, 0);
      acc[1][cf] = __builtin_amdgcn_mfma_f32_16x16x32_bf16(a1, breg[cf][ks], acc[1][cf], 0, 0, 0);
    }
  }
#pragma unroll
  for (int cf = 0; cf < 2; ++cf) {
    int n = c0 + cf * 16 + row;
    float bias = (n < 512) ? bg1[n] : 0.f;
#pragma unroll
    for (int rf = 0; rf < 2; ++rf)
#pragma unroll
      for (int r = 0; r < 4; ++r) {
        int mrow = m0 + rf * 16 + (lane >> 4) * 4 + r;
        g_all[((size_t)mrow << 10) + n] = f2bf(acc[rf][cf][r] + bias);
      }
  }
}

// ---------------- k3: all_gp[hi][b] = sum over (ii in half, j) — r3 verbatim -
__global__ __launch_bounds__(512, 2) void k3(const unsigned short* __restrict__ g_all,
                                             const unsigned short* __restrict__ Wg2T,
                                             const float* __restrict__ bg2,
                                             float* __restrict__ all_gp) {
  __shared__ unsigned char ldsH[2][32768];   // [32][512] bf16 swizzled, dbuf
  int b = blockIdx.x >> 1, hi = blockIdx.x & 1;
  int ii0 = hi * 16;
  int tid = threadIdx.x, lane = tid & 63, w = tid >> 6;
  int row = lane & 15, kg = (lane >> 4) * 8;
  int cb = w * 32;
  int p = tid >> 4, kslot = tid & 15;

  short8 breg[2][16];
#pragma unroll
  for (int cf = 0; cf < 2; ++cf)
#pragma unroll
    for (int ks = 0; ks < 16; ++ks)
      breg[cf][ks] = *reinterpret_cast<const short8*>(
          Wg2T + (size_t)(cb + cf * 16 + row) * 512 + ks * 32 + kg);

  float gjf[32];
  {
    const unsigned short* gjp = g_all + ((size_t)(b * 32 + p) << 10) + 512 + kslot * 8;
#pragma unroll
    for (int q = 0; q < 4; ++q) {
      short8 gv0 = *reinterpret_cast<const short8*>(gjp + q * 128);
#pragma unroll
      for (int e = 0; e < 8; ++e) gjf[q * 8 + e] = bf2f((unsigned short)gv0[e]);
    }
  }
  float biasv[2] = { bg2[cb + row], bg2[cb + 16 + row] };
  float accsum[2] = { 0.f, 0.f };

  short8 gv[4];
  auto hload = [&](int ii) {
    const unsigned short* gi = g_all + ((size_t)(b * 32 + ii) << 10) + kslot * 8;
#pragma unroll
    for (int q = 0; q < 4; ++q)
      gv[q] = *reinterpret_cast<const short8*>(gi + q * 128);
  };
  auto hstore = [&](int buf) {
    unsigned char* hb = &ldsH[buf][0] + p * 1024;
#pragma unroll
    for (int q = 0; q < 4; ++q) {
      uint4 pv;
      float f0 = fmaxf(bf2f((unsigned short)gv[q][0]) + gjf[q * 8 + 0], 0.f);
      float f1 = fmaxf(bf2f((unsigned short)gv[q][1]) + gjf[q * 8 + 1], 0.f);
      float f2 = fmaxf(bf2f((unsigned short)gv[q][2]) + gjf[q * 8 + 2], 0.f);
      float f3 = fmaxf(bf2f((unsigned short)gv[q][3]) + gjf[q * 8 + 3], 0.f);
      float f4 = fmaxf(bf2f((unsigned short)gv[q][4]) + gjf[q * 8 + 4], 0.f);
      float f5 = fmaxf(bf2f((unsigned short)gv[q][5]) + gjf[q * 8 + 5], 0.f);
      float f6 = fmaxf(bf2f((unsigned short)gv[q][6]) + gjf[q * 8 + 6], 0.f);
      float f7 = fmaxf(bf2f((unsigned short)gv[q][7]) + gjf[q * 8 + 7], 0.f);
      pv.x = pack_bf2(f0, f1); pv.y = pack_bf2(f2, f3);
      pv.z = pack_bf2(f4, f5); pv.w = pack_bf2(f6, f7);
      int addr = (kslot * 16 + q * 256) ^ ((p & 7) << 4);
      *reinterpret_cast<uint4*>(hb + addr) = pv;
    }
  };

  hload(ii0);
  hstore(0);
  __syncthreads();

  for (int it = 0; it < 16; ++it) {
    if (it < 15) hload(ii0 + it + 1);
    const unsigned char* hc = &ldsH[it & 1][0];
    f32x4 acc[2][2] = {{{0,0,0,0},{0,0,0,0}},{{0,0,0,0},{0,0,0,0}}};
    short8 a0 = *reinterpret_cast<const short8*>(hc + ((row * 1024 + kg * 2) ^ ((row & 7) << 4)));
    short8 a1 = *reinterpret_cast<const short8*>(hc + (((16 + row) * 1024 + kg * 2) ^ ((row & 7) << 4)));
#pragma unroll
    for (int ks = 0; ks < 16; ++ks) {
      short8 c0v = a0, c1v = a1;
      if (ks < 15) {
        a0 = *reinterpret_cast<const short8*>(hc + ((row * 1024 + (ks + 1) * 64 + kg * 2) ^ ((row & 7) << 4)));
        a1 = *reinterpret_cast<const short8*>(hc + (((16 + row) * 1024 + (ks + 1) * 64 + kg * 2) ^ ((row & 7) << 4)));
      }
      __builtin_amdgcn_s_setprio(1);
      acc[0][0] = __builtin_amdgcn_mfma_f32_16x16x32_bf16(c0v, breg[0][ks], acc[0][0], 0, 0, 0);
      acc[0][1] = __builtin_amdgcn_mfma_f32_16x16x32_bf16(c0v, breg[1][ks], acc[0][1], 0, 0, 0);
      acc[1][0] = __builtin_amdgcn_mfma_f32_16x16x32_bf16(c1v, breg[0][ks], acc[1][0], 0, 0, 0);
      acc[1][1] = __builtin_amdgcn_mfma_f32_16x16x32_bf16(c1v, breg[1][ks], acc[1][1], 0, 0, 0);
      __builtin_amdgcn_s_setprio(0);
    }
    if (it < 15) hstore((it + 1) & 1);
#pragma unroll
    for (int cf = 0; cf < 2; ++cf)
#pragma unroll
      for (int rf = 0; rf < 2; ++rf)
#pragma unroll
        for (int r = 0; r < 4; ++r)
          accsum[cf] += fmaxf(acc[rf][cf][r] + biasv[cf], 0.f);
    __syncthreads();
  }

#pragma unroll
  for (int cf = 0; cf < 2; ++cf) {
    accsum[cf] += __shfl_xor(accsum[cf], 16, 64);
    accsum[cf] += __shfl_xor(accsum[cf], 32, 64);
  }
  if ((lane >> 4) == 0) {
#pragma unroll
    for (int cf = 0; cf < 2; ++cf)
      all_gp[(size_t)(hi * 128 + b) * 256 + cb + cf * 16 + lane] = accsum[cf];
  }
}

// ---------------- k4: head (MFMA), sums 2 all_gp partials --------------------
__global__ __launch_bounds__(512) void k4(const float* __restrict__ all_gp,
                                          const unsigned short* __restrict__ WfT,
                                          const float* __restrict__ bfv,
                                          const float* __restrict__ Wy,
                                          const float* __restrict__ by,
                                          float* __restrict__ out) {
  __shared__ unsigned char As[8192];      // [16][256] bf16 swizzled
  __shared__ float fh[16][264];
  __shared__ float wys[1024];
  __shared__ float yvs[16][4];
  int tid = threadIdx.x, lane = tid & 63, w = tid >> 6;
  int row = lane & 15, kg = (lane >> 4) * 8;
  int m0 = blockIdx.x * 16;

  {
    int r = tid >> 5, c8 = (tid & 31) * 8;
    float s[8];
#pragma unroll
    for (int e = 0; e < 8; ++e) s[e] = 0.f;
#pragma unroll
    for (int q = 0; q < 2; ++q) {
      const float* p0 = all_gp + (size_t)(q * 128 + m0 + r) * 256 + c8;
      float4 a0 = *reinterpret_cast<const float4*>(p0);
      float4 a1 = *reinterpret_cast<const float4*>(p0 + 4);
      s[0] += a0.x; s[1] += a0.y; s[2] += a0.z; s[3] += a0.w;
      s[4] += a1.x; s[5] += a1.y; s[6] += a1.z; s[7] += a1.w;
    }
    uint4 pv;
    pv.x = pack_bf2(s[0], s[1]); pv.y = pack_bf2(s[2], s[3]);
    pv.z = pack_bf2(s[4], s[5]); pv.w = pack_bf2(s[6], s[7]);
    int addr = (r * 512 + c8 * 2) ^ ((r & 7) << 4);
    *reinterpret_cast<uint4*>(&As[addr]) = pv;
  }
  wys[tid] = Wy[tid];
  wys[tid + 512] = Wy[tid + 512];
  short8 breg[2][8];
#pragma unroll
  for (int cf = 0; cf < 2; ++cf)
#pragma unroll
    for (int ks = 0; ks < 8; ++ks)
      breg[cf][ks] = *reinterpret_cast<const short8*>(
          WfT + (size_t)(w * 32 + cf * 16 + row) * 256 + ks * 32 + kg);
  __syncthreads();

  f32x4 acc[2] = {{0,0,0,0},{0,0,0,0}};
#pragma unroll
  for (int ks = 0; ks < 8; ++ks) {
    int aoff = (row * 512 + ks * 64 + kg * 2) ^ ((row & 7) << 4);
    short8 af = *reinterpret_cast<const short8*>(&As[aoff]);
    acc[0] = __builtin_amdgcn_mfma_f32_16x16x32_bf16(af, breg[0][ks], acc[0], 0, 0, 0);
    acc[1] = __builtin_amdgcn_mfma_f32_16x16x32_bf16(af, breg[1][ks], acc[1], 0, 0, 0);
  }
#pragma unroll
  for (int cf = 0; cf < 2; ++cf) {
    int col = w * 32 + cf * 16 + row;
    float bias = bfv[col];
#pragma unroll
    for (int r = 0; r < 4; ++r)
      fh[(lane >> 4) * 4 + r][col] = fmaxf(acc[cf][r] + bias, 0.f);
  }
  __syncthreads();

  if (tid < 64) {
    int r = tid >> 2, o = tid & 3;
    float y = by[o];
#pragma unroll 4
    for (int k = 0; k < 256; ++k) y += fh[r][k] * wys[k * 4 + o];
    yvs[r][o] = y;
    out[(m0 + r) * 4 + o] = y;
  }
  __syncthreads();
  if (tid < 16) {
    int am = 0;
    float best = yvs[tid][0];
#pragma unroll
    for (int o = 1; o < 4; ++o)
      if (yvs[tid][o] > best) { best = yvs[tid][o]; am = o; }
    out[512 + m0 + tid] = (float)am;
  }
}

extern "C" void kernel_launch(void* const* d_in, const int* in_sizes, int n_in,
                              void* d_out, int out_size, void* d_ws, size_t ws_size,
                              hipStream_t stream) {
  const float* x     = (const float*)d_in[0];
  const float* We1   = (const float*)d_in[1];
  const float* be1   = (const float*)d_in[2];
  const float* We2   = (const float*)d_in[3];
  const float* be2   = (const float*)d_in[4];
  const float* gamma = (const float*)d_in[5];
  const float* beta  = (const float*)d_in[6];
  const float* Wg1   = (const float*)d_in[7];
  const float* bg1   = (const float*)d_in[8];
  const float* Wg2   = (const float*)d_in[9];
  const float* bg2   = (const float*)d_in[10];
  const float* Wf    = (const float*)d_in[11];
  const float* bff   = (const float*)d_in[12];
  const float* Wy    = (const float*)d_in[13];
  const float* by    = (const float*)d_in[14];

  char* ws = (char*)d_ws;
  unsigned short* g_all = (unsigned short*)(ws + 0);          // 8 MB
  unsigned short* We1T  = (unsigned short*)(ws + 8388608);    // 512 KB
  unsigned short* We2T  = (unsigned short*)(ws + 8912896);    // 64 KB (+128KB slack for k1f w>=4 reads)
  unsigned short* Wg1T  = (unsigned short*)(ws + 9175040);    // 320 KB
  unsigned short* Wg2T  = (unsigned short*)(ws + 9502720);    // 256 KB
  unsigned short* WfT   = (unsigned short*)(ws + 9764864);    // 128 KB
  float*          all_gp= (float*)(ws + 9895936);             // 256 KB [2][128][256]
  unsigned short* zc    = (unsigned short*)(ws + 10158080);   // 1.31 MB
  float*          out   = (float*)d_out;

  k0_prep<<<640, 256, 0, stream>>>(We1, We2, Wg1, Wg2, Wf, We1T, We2T, Wg1T, Wg2T, WfT);
  k1f<<<128, 512, 0, stream>>>(x, We1T, be1, We2T, be2, gamma, beta, zc);
  k2b<<<512, 512, 0, stream>>>(zc, Wg1T, bg1, g_all);
  k3<<<256, 512, 0, stream>>>(g_all, Wg2T, bg2, all_gp);
  k4<<<8, 512, 0, stream>>>(all_gp, WfT, bff, Wy, by, out);
}